// Round 2
// baseline (173.863 us; speedup 1.0000x reference)
//
#include <hip/hip_runtime.h>
#include <cstddef>
#include <cstdint>

#define BB 8
#define SS 256
#define EE 256
#define NN1 16
#define NN2 16
#define DD 100
#define QQ 768

// ---------------------------------------------------------------------------
// prep: blocks 0..15 -> per (b, layer) compute qk = 0.1 * Wk^T tanh(Wq q0 + bq)
//       blocks 16..23 -> per b inclusive scan of (input_ent != 0) -> rank (-1 = masked)
// ---------------------------------------------------------------------------
__global__ __launch_bounds__(256) void prep_kernel(
    const float* __restrict__ q, const int* __restrict__ ent,
    const float* __restrict__ Wq2, const float* __restrict__ bq2, const float* __restrict__ Wk2,
    const float* __restrict__ Wq1, const float* __restrict__ bq1, const float* __restrict__ Wk1,
    float* __restrict__ qk2o, float* __restrict__ qk1o, int* __restrict__ rk)
{
    const int blk = blockIdx.x, t = threadIdx.x;
    if (blk < 16) {
        const int b = blk >> 1, layer = blk & 1;
        const float* Wq = layer ? Wq1 : Wq2;
        const float* bq = layer ? bq1 : bq2;
        const float* Wk = layer ? Wk1 : Wk2;
        float* qko      = layer ? qk1o : qk2o;
        __shared__ float s_q[QQ];
        __shared__ float s_qi[DD];
        for (int i = t; i < QQ; i += 256) s_q[i] = q[(size_t)b * SS * QQ + i]; // q[b,0,:]
        __syncthreads();
        const int r = t & 7;
        for (int d = t >> 3; d < DD; d += 32) {
            float acc = 0.f;
            for (int i = r; i < QQ; i += 8) acc += Wq[(size_t)d * QQ + i] * s_q[i];
            acc += __shfl_xor(acc, 1, 8);
            acc += __shfl_xor(acc, 2, 8);
            acc += __shfl_xor(acc, 4, 8);
            if (r == 0) s_qi[d] = tanhf(acc + bq[d]);
        }
        __syncthreads();
        if (t < DD) {
            float acc = 0.f;
            for (int d = 0; d < DD; ++d) acc += s_qi[d] * Wk[d * DD + t]; // (Wk^T q_i)[t]
            qko[b * DD + t] = 0.1f * acc;   // fold 1/sqrt(100)
        }
    } else {
        const int b = blk - 16;
        __shared__ int s_m[SS];
        const int m = (ent[b * SS + t] != 0) ? 1 : 0;
        s_m[t] = m;
        __syncthreads();
        for (int off = 1; off < SS; off <<= 1) {
            const int add = (t >= off) ? s_m[t - off] : 0;
            __syncthreads();
            s_m[t] += add;
            __syncthreads();
        }
        int rank = s_m[t] - 1;
        rank = rank < 0 ? 0 : (rank > EE - 1 ? EE - 1 : rank);
        rk[b * SS + t] = m ? rank : -1;
    }
}

// ---------------------------------------------------------------------------
// main: one block per (b,e). 17 pipelined tiles: 16 x layer-2 (n1), then layer-1.
// Reg-staged prefetch: loads for tile it+1 issued right after tile it is staged,
// so HBM latency hides under tile it's compute. 3 barriers per tile.
// ---------------------------------------------------------------------------
__global__ __launch_bounds__(256) void main_kernel(
    const float* __restrict__ k1, const float* __restrict__ v1,
    const float* __restrict__ k2, const float* __restrict__ v2,
    const float* __restrict__ qk1g, const float* __restrict__ qk2g,
    float* __restrict__ comb)
{
    const int be = blockIdx.x;
    const int b  = be >> 8;
    const int t  = threadIdx.x;

    __shared__ float s_k[NN2 * 104];     // k rows padded to 104 floats (bank-conflict-free dot)
    __shared__ float s_v[NN2 * DD];
    __shared__ float s_c2[NN1 * DD];     // layer-2 outputs
    __shared__ float s_qk2[DD];
    __shared__ float s_qk1[DD];
    __shared__ float s_logit[16];
    float4* sk4 = reinterpret_cast<float4*>(s_k);
    float4* sv4 = reinterpret_cast<float4*>(s_v);

    if (t < DD) { s_qk2[t] = qk2g[b * DD + t]; s_qk1[t] = qk1g[b * DD + t]; }

    const int gi = t >> 4;   // row (n2 / n1) handled by this 16-lane group
    const int rr = t & 15;
    const int i1 = t + 256;  // second staged float4 index (threads t<144)

    // k-chunk float4 i -> padded LDS float4 slot (row i/25 has 26 float4s)
    const int ks0 = (t  / 25) * 26 + (t  % 25);
    const int ks1 = (i1 / 25) * 26 + (i1 % 25);

    float4 rk0, rk1, rv0, rv1;
    {   // prologue: issue loads for tile 0
        const float4* gk = reinterpret_cast<const float4*>(k2 + (size_t)be * NN1 * (NN2 * DD));
        const float4* gv = reinterpret_cast<const float4*>(v2 + (size_t)be * NN1 * (NN2 * DD));
        rk0 = gk[t]; rv0 = gv[t];
        if (t < 144) { rk1 = gk[i1]; rv1 = gv[i1]; }
    }

    for (int it = 0; it <= NN1; ++it) {
        __syncthreads();                       // previous tile's compute done (and prologue visible)
        // stage regs -> LDS
        sk4[ks0] = rk0;
        sv4[t]   = rv0;
        if (t < 144) { sk4[ks1] = rk1; sv4[i1] = rv1; }
        __syncthreads();

        // issue next tile's loads (hide under compute below)
        if (it < NN1) {
            const float* kb = (it < NN1 - 1) ? k2 + ((size_t)(be * NN1 + it + 1)) * (NN2 * DD)
                                             : k1 + (size_t)be * (NN1 * DD);
            const float* vb = (it < NN1 - 1) ? v2 + ((size_t)(be * NN1 + it + 1)) * (NN2 * DD)
                                             : v1 + (size_t)be * (NN1 * DD);
            const float4* gk = reinterpret_cast<const float4*>(kb);
            const float4* gv = reinterpret_cast<const float4*>(vb);
            rk0 = gk[t]; rv0 = gv[t];
            if (t < 144) { rk1 = gk[i1]; rv1 = gv[i1]; }
        }

        // logits: 16 lanes per row
        const float* qk = (it == NN1) ? s_qk1 : s_qk2;
        float acc = 0.f;
        for (int d = rr; d < DD; d += 16) acc += s_k[gi * 104 + d] * qk[d];
        acc += __shfl_xor(acc, 1, 16);
        acc += __shfl_xor(acc, 2, 16);
        acc += __shfl_xor(acc, 4, 16);
        acc += __shfl_xor(acc, 8, 16);
        if (rr == 0) {
            float lg = acc;
            if (lg == 0.0f) lg = -10000.0f;
            s_logit[gi] = lg >= 0.f ? lg : 0.01f * lg;   // leaky_relu
        }
        __syncthreads();

        // softmax, redundant in every wave (no extra barrier)
        float lg = s_logit[t & 15];
        float mx = lg;
        mx = fmaxf(mx, __shfl_xor(mx, 1, 16));
        mx = fmaxf(mx, __shfl_xor(mx, 2, 16));
        mx = fmaxf(mx, __shfl_xor(mx, 4, 16));
        mx = fmaxf(mx, __shfl_xor(mx, 8, 16));
        float e = __expf(lg - mx);
        float sm = e;
        sm += __shfl_xor(sm, 1, 16);
        sm += __shfl_xor(sm, 2, 16);
        sm += __shfl_xor(sm, 4, 16);
        sm += __shfl_xor(sm, 8, 16);
        float p = e / sm;
        if (p == 0.0625f) p = 0.f;             // where(attn == 1/n, 0)
        float pn[16];
        #pragma unroll
        for (int n = 0; n < 16; ++n) pn[n] = __shfl(p, n, 64);  // lane n holds p[n]

        // PV
        if (it < NN1) {
            if (t < DD) {
                float a = 0.f;
                #pragma unroll
                for (int n = 0; n < 16; ++n) a += pn[n] * s_v[n * DD + t];
                s_c2[it * DD + t] = a;
            }
        } else {
            if (t < 2 * DD) {
                float a = 0.f;
                if (t < DD) {
                    #pragma unroll
                    for (int n = 0; n < 16; ++n) a += pn[n] * s_v[n * DD + t];
                } else {
                    #pragma unroll
                    for (int n = 0; n < 16; ++n) a += pn[n] * s_c2[n * DD + (t - DD)];
                }
                comb[(size_t)be * (2 * DD) + t] = a;
            }
        }
    }
}

// ---------------------------------------------------------------------------
// gather: one block per (b,s)
// ---------------------------------------------------------------------------
__global__ __launch_bounds__(64) void gather_kernel(
    const float* __restrict__ comb, const int* __restrict__ rk, float* __restrict__ out)
{
    const int bs = blockIdx.x;
    const int b  = bs >> 8;
    const int t  = threadIdx.x;
    const int r  = rk[bs];
    float* o = out + (size_t)bs * (2 * DD);
    if (r < 0) {
        for (int d = t; d < 2 * DD; d += 64) o[d] = 0.f;
    } else {
        const float* src = comb + (size_t)(b * EE + r) * (2 * DD);
        for (int d = t; d < 2 * DD; d += 64) o[d] = src[d];
    }
}

extern "C" void kernel_launch(void* const* d_in, const int* in_sizes, int n_in,
                              void* d_out, int out_size, void* d_ws, size_t ws_size,
                              hipStream_t stream)
{
    const int*   ent = (const int*)d_in[0];
    const float* q   = (const float*)d_in[1];
    const float* k1  = (const float*)d_in[2];
    const float* v1  = (const float*)d_in[3];
    const float* k2  = (const float*)d_in[4];
    const float* v2  = (const float*)d_in[5];
    const float* Wq2 = (const float*)d_in[6];
    const float* bq2 = (const float*)d_in[7];
    const float* Wk2 = (const float*)d_in[8];
    const float* Wq1 = (const float*)d_in[9];
    const float* bq1 = (const float*)d_in[10];
    const float* Wk1 = (const float*)d_in[11];
    float* out = (float*)d_out;

    float* ws   = (float*)d_ws;
    float* qk2  = ws;                    // 800 floats
    float* qk1  = ws + 1024;             // 800 floats
    float* comb = ws + 4096;             // 8*256*200 = 409600 floats
    int*   rk   = (int*)(ws + 4096 + 409600);  // 2048 ints

    prep_kernel<<<24, 256, 0, stream>>>(q, ent, Wq2, bq2, Wk2, Wq1, bq1, Wk1, qk2, qk1, rk);
    main_kernel<<<BB * EE, 256, 0, stream>>>(k1, v1, k2, v2, qk1, qk2, comb);
    gather_kernel<<<BB * SS, 64, 0, stream>>>(comb, rk, out);
}

// Round 3
// 159.733 us; speedup vs baseline: 1.0885x; 1.0885x over previous
//
#include <hip/hip_runtime.h>
#include <cstddef>
#include <cstdint>

#define BB 8
#define SS 256
#define EE 256
#define NN1 16
#define NN2 16
#define DD 100
#define QQ 768

// ---------------------------------------------------------------------------
// prep: blocks 0..15 -> per (b, layer) compute qk = 0.1 * Wk^T tanh(Wq q0 + bq)
//       blocks 16..23 -> per b inclusive scan of (input_ent != 0) -> rank (-1 = masked)
// ---------------------------------------------------------------------------
__global__ __launch_bounds__(256) void prep_kernel(
    const float* __restrict__ q, const int* __restrict__ ent,
    const float* __restrict__ Wq2, const float* __restrict__ bq2, const float* __restrict__ Wk2,
    const float* __restrict__ Wq1, const float* __restrict__ bq1, const float* __restrict__ Wk1,
    float* __restrict__ qk2o, float* __restrict__ qk1o, int* __restrict__ rk)
{
    const int blk = blockIdx.x, t = threadIdx.x;
    if (blk < 16) {
        const int b = blk >> 1, layer = blk & 1;
        const float* Wq = layer ? Wq1 : Wq2;
        const float* bq = layer ? bq1 : bq2;
        const float* Wk = layer ? Wk1 : Wk2;
        float* qko      = layer ? qk1o : qk2o;
        __shared__ float s_q[QQ];
        __shared__ float s_qi[DD];
        for (int i = t; i < QQ; i += 256) s_q[i] = q[(size_t)b * SS * QQ + i]; // q[b,0,:]
        __syncthreads();
        const int r = t & 7;
        for (int d = t >> 3; d < DD; d += 32) {
            float acc = 0.f;
            for (int i = r; i < QQ; i += 8) acc += Wq[(size_t)d * QQ + i] * s_q[i];
            acc += __shfl_xor(acc, 1, 8);
            acc += __shfl_xor(acc, 2, 8);
            acc += __shfl_xor(acc, 4, 8);
            if (r == 0) s_qi[d] = tanhf(acc + bq[d]);
        }
        __syncthreads();
        if (t < DD) {
            float acc = 0.f;
            for (int d = 0; d < DD; ++d) acc += s_qi[d] * Wk[d * DD + t]; // (Wk^T q_i)[t]
            qko[b * DD + t] = 0.1f * acc;   // fold 1/sqrt(100)
        }
    } else {
        const int b = blk - 16;
        __shared__ int s_m[SS];
        const int m = (ent[b * SS + t] != 0) ? 1 : 0;
        s_m[t] = m;
        __syncthreads();
        for (int off = 1; off < SS; off <<= 1) {
            const int add = (t >= off) ? s_m[t - off] : 0;
            __syncthreads();
            s_m[t] += add;
            __syncthreads();
        }
        int rank = s_m[t] - 1;
        rank = rank < 0 ? 0 : (rank > EE - 1 ? EE - 1 : rank);
        rk[b * SS + t] = m ? rank : -1;
    }
}

// ---------------------------------------------------------------------------
// dk2: one block per (bb,e,n1). No K/V staging (zero reuse) — direct global
// reads, 128 B LDS, 2 barriers. c2 indexed by chunk-local bb.
// ---------------------------------------------------------------------------
__global__ __launch_bounds__(256) void dk2_kernel(
    const float* __restrict__ k2, const float* __restrict__ v2,
    const float* __restrict__ qk2g, float* __restrict__ c2, int b0)
{
    const int blk = blockIdx.x;          // (bb*256 + e)*16 + n1
    const int n1  = blk & 15;
    const int bbe = blk >> 4;            // bb*256 + e
    const int b   = b0 + (bbe >> 8);
    const int t   = threadIdx.x;
    const int gi  = t >> 4;              // n2 row for this 16-lane group
    const int rr  = t & 15;

    __shared__ float s_logit[16];
    __shared__ float s_p[16];

    const size_t base = ((size_t)(((b << 8) | (bbe & 255)) * 16 + n1)) * (size_t)(NN2 * DD);

    // logits: 16 lanes per n2 row, k read directly from global
    const float* krow = k2 + base + gi * DD;
    const float* qk   = qk2g + b * DD;
    float acc = 0.f;
    #pragma unroll
    for (int j = 0; j < 7; ++j) {
        const int d = rr + 16 * j;
        if (d < DD) acc += krow[d] * qk[d];
    }
    acc += __shfl_xor(acc, 1, 16);
    acc += __shfl_xor(acc, 2, 16);
    acc += __shfl_xor(acc, 4, 16);
    acc += __shfl_xor(acc, 8, 16);
    if (rr == 0) {
        float lg = acc;
        if (lg == 0.0f) lg = -10000.0f;
        s_logit[gi] = lg >= 0.f ? lg : 0.01f * lg;   // leaky_relu
    }
    __syncthreads();

    // softmax (redundant per wave, no extra barrier)
    float lg = s_logit[t & 15];
    float mx = lg;
    mx = fmaxf(mx, __shfl_xor(mx, 1, 16));
    mx = fmaxf(mx, __shfl_xor(mx, 2, 16));
    mx = fmaxf(mx, __shfl_xor(mx, 4, 16));
    mx = fmaxf(mx, __shfl_xor(mx, 8, 16));
    const float e = __expf(lg - mx);
    float sm = e;
    sm += __shfl_xor(sm, 1, 16);
    sm += __shfl_xor(sm, 2, 16);
    sm += __shfl_xor(sm, 4, 16);
    sm += __shfl_xor(sm, 8, 16);
    float p = e / sm;
    if (p == 0.0625f) p = 0.f;           // where(attn == 1/n, 0)
    if (t < 16) s_p[t] = p;
    __syncthreads();

    // PV: v read directly from global, write c2 (chunk-local)
    if (t < DD) {
        const float* vb = v2 + base;
        float a = 0.f;
        #pragma unroll
        for (int n = 0; n < NN2; ++n) a += s_p[n] * vb[n * DD + t];
        c2[((size_t)bbe * NN1 + n1) * DD + t] = a;
    }
}

// ---------------------------------------------------------------------------
// dk1: one block per (bb,e). Reads k1/v1 direct + c2 from ws, writes comb[b,e,0:200].
// ---------------------------------------------------------------------------
__global__ __launch_bounds__(256) void dk1_kernel(
    const float* __restrict__ k1, const float* __restrict__ v1,
    const float* __restrict__ c2, const float* __restrict__ qk1g,
    float* __restrict__ comb, int b0)
{
    const int bbe = blockIdx.x;          // bb*256 + e
    const int b   = b0 + (bbe >> 8);
    const int be  = (b << 8) | (bbe & 255);
    const int t   = threadIdx.x;
    const int gi  = t >> 4;              // n1 row
    const int rr  = t & 15;

    __shared__ float s_logit[16];
    __shared__ float s_p[16];

    const size_t base = (size_t)be * (NN1 * DD);

    const float* krow = k1 + base + gi * DD;
    const float* qk   = qk1g + b * DD;
    float acc = 0.f;
    #pragma unroll
    for (int j = 0; j < 7; ++j) {
        const int d = rr + 16 * j;
        if (d < DD) acc += krow[d] * qk[d];
    }
    acc += __shfl_xor(acc, 1, 16);
    acc += __shfl_xor(acc, 2, 16);
    acc += __shfl_xor(acc, 4, 16);
    acc += __shfl_xor(acc, 8, 16);
    if (rr == 0) {
        float lg = acc;
        if (lg == 0.0f) lg = -10000.0f;
        s_logit[gi] = lg >= 0.f ? lg : 0.01f * lg;
    }
    __syncthreads();

    float lg = s_logit[t & 15];
    float mx = lg;
    mx = fmaxf(mx, __shfl_xor(mx, 1, 16));
    mx = fmaxf(mx, __shfl_xor(mx, 2, 16));
    mx = fmaxf(mx, __shfl_xor(mx, 4, 16));
    mx = fmaxf(mx, __shfl_xor(mx, 8, 16));
    const float e = __expf(lg - mx);
    float sm = e;
    sm += __shfl_xor(sm, 1, 16);
    sm += __shfl_xor(sm, 2, 16);
    sm += __shfl_xor(sm, 4, 16);
    sm += __shfl_xor(sm, 8, 16);
    float p = e / sm;
    if (p == 0.0625f) p = 0.f;
    if (t < 16) s_p[t] = p;
    __syncthreads();

    if (t < 2 * DD) {
        float a = 0.f;
        if (t < DD) {
            const float* vb = v1 + base;
            #pragma unroll
            for (int n = 0; n < NN1; ++n) a += s_p[n] * vb[n * DD + t];
        } else {
            const int d = t - DD;
            const float* cb = c2 + (size_t)bbe * (NN1 * DD);
            #pragma unroll
            for (int n = 0; n < NN1; ++n) a += s_p[n] * cb[n * DD + d];
        }
        comb[(size_t)be * (2 * DD) + t] = a;
    }
}

// ---------------------------------------------------------------------------
// gather: one block per (b,s)
// ---------------------------------------------------------------------------
__global__ __launch_bounds__(64) void gather_kernel(
    const float* __restrict__ comb, const int* __restrict__ rk, float* __restrict__ out)
{
    const int bs = blockIdx.x;
    const int b  = bs >> 8;
    const int t  = threadIdx.x;
    const int r  = rk[bs];
    float* o = out + (size_t)bs * (2 * DD);
    if (r < 0) {
        for (int d = t; d < 2 * DD; d += 64) o[d] = 0.f;
    } else {
        const float* src = comb + (size_t)(b * EE + r) * (2 * DD);
        for (int d = t; d < 2 * DD; d += 64) o[d] = src[d];
    }
}

extern "C" void kernel_launch(void* const* d_in, const int* in_sizes, int n_in,
                              void* d_out, int out_size, void* d_ws, size_t ws_size,
                              hipStream_t stream)
{
    const int*   ent = (const int*)d_in[0];
    const float* q   = (const float*)d_in[1];
    const float* k1  = (const float*)d_in[2];
    const float* v1  = (const float*)d_in[3];
    const float* k2  = (const float*)d_in[4];
    const float* v2  = (const float*)d_in[5];
    const float* Wq2 = (const float*)d_in[6];
    const float* bq2 = (const float*)d_in[7];
    const float* Wk2 = (const float*)d_in[8];
    const float* Wq1 = (const float*)d_in[9];
    const float* bq1 = (const float*)d_in[10];
    const float* Wk1 = (const float*)d_in[11];
    float* out = (float*)d_out;

    float* ws   = (float*)d_ws;
    float* qk2  = ws;                          // [0, 1024)
    float* qk1  = ws + 1024;                   // [1024, 2048)
    int*   rk   = (int*)(ws + 2048);           // [2048, 4096) as ints
    float* comb = ws + 4096;                   // [4096, 4096+409600)
    float* c2   = ws + 4096 + 409600;          // per-b chunks of 409600 floats

    // batches per chunk, limited by workspace (deterministic in ws_size)
    const size_t fixed = 4096 + 409600;        // floats
    const size_t perb  = (size_t)EE * NN1 * DD; // 409600 floats per batch
    size_t wsf = ws_size / sizeof(float);
    int kb = (wsf > fixed) ? (int)((wsf - fixed) / perb) : 1;
    if (kb < 1) kb = 1;
    if (kb > BB) kb = BB;

    prep_kernel<<<24, 256, 0, stream>>>(q, ent, Wq2, bq2, Wk2, Wq1, bq1, Wk1, qk2, qk1, rk);
    for (int b0 = 0; b0 < BB; b0 += kb) {
        const int nb = (BB - b0 < kb) ? (BB - b0) : kb;
        dk2_kernel<<<nb * EE * NN1, 256, 0, stream>>>(k2, v2, qk2, c2, b0);
        dk1_kernel<<<nb * EE,       256, 0, stream>>>(k1, v1, c2, qk1, comb, b0);
    }
    gather_kernel<<<BB * SS, 64, 0, stream>>>(comb, rk, out);
}

// Round 4
// 146.513 us; speedup vs baseline: 1.1867x; 1.0902x over previous
//
#include <hip/hip_runtime.h>
#include <cstddef>
#include <cstdint>

#define BB 8
#define SS 256
#define EE 256
#define NN1 16
#define NN2 16
#define DD 100
#define QQ 768

__device__ __forceinline__ float dot4(float4 a, float4 b) {
    return a.x * b.x + a.y * b.y + a.z * b.z + a.w * b.w;
}

// ---------------------------------------------------------------------------
// prep: blocks 0..15 -> per (b, layer) compute qk = 0.1 * Wk^T tanh(Wq q0 + bq)
//       blocks 16..23 -> per b inclusive scan of (input_ent != 0) -> rank (-1 = masked)
// ---------------------------------------------------------------------------
__global__ __launch_bounds__(256) void prep_kernel(
    const float* __restrict__ q, const int* __restrict__ ent,
    const float* __restrict__ Wq2, const float* __restrict__ bq2, const float* __restrict__ Wk2,
    const float* __restrict__ Wq1, const float* __restrict__ bq1, const float* __restrict__ Wk1,
    float* __restrict__ qk2o, float* __restrict__ qk1o, int* __restrict__ rk)
{
    const int blk = blockIdx.x, t = threadIdx.x;
    if (blk < 16) {
        const int b = blk >> 1, layer = blk & 1;
        const float* Wq = layer ? Wq1 : Wq2;
        const float* bq = layer ? bq1 : bq2;
        const float* Wk = layer ? Wk1 : Wk2;
        float* qko      = layer ? qk1o : qk2o;
        __shared__ float s_q[QQ];
        __shared__ float s_qi[DD];
        for (int i = t; i < QQ; i += 256) s_q[i] = q[(size_t)b * SS * QQ + i]; // q[b,0,:]
        __syncthreads();
        const float4* sq4 = (const float4*)s_q;
        const int r = t & 7;
        for (int d = t >> 3; d < DD; d += 32) {
            const float4* wq4 = (const float4*)(Wq + (size_t)d * QQ);
            float acc = 0.f;
            for (int c = r; c < QQ / 4; c += 8) acc += dot4(wq4[c], sq4[c]);
            acc += __shfl_xor(acc, 1, 8);
            acc += __shfl_xor(acc, 2, 8);
            acc += __shfl_xor(acc, 4, 8);
            if (r == 0) s_qi[d] = tanhf(acc + bq[d]);
        }
        __syncthreads();
        if (t < DD) {
            float acc = 0.f;
            for (int d = 0; d < DD; ++d) acc += s_qi[d] * Wk[d * DD + t]; // (Wk^T q_i)[t]
            qko[b * DD + t] = 0.1f * acc;   // fold 1/sqrt(100)
        }
    } else {
        const int b = blk - 16;
        __shared__ int s_m[SS];
        const int m = (ent[b * SS + t] != 0) ? 1 : 0;
        s_m[t] = m;
        __syncthreads();
        for (int off = 1; off < SS; off <<= 1) {
            const int add = (t >= off) ? s_m[t - off] : 0;
            __syncthreads();
            s_m[t] += add;
            __syncthreads();
        }
        int rank = s_m[t] - 1;
        rank = rank < 0 ? 0 : (rank > EE - 1 ? EE - 1 : rank);
        rk[b * SS + t] = m ? rank : -1;
    }
}

// ---------------------------------------------------------------------------
// dk2: one block per (bb, e, n1-pair). All k/v loads are coalesced float4,
// issued together at block start (whole 25.6 KB in flight). 2 barriers.
// Waves 0-1 finish tile a (rows 0-15), waves 2-3 tile b (rows 16-31).
// ---------------------------------------------------------------------------
__global__ __launch_bounds__(256) void dk2_kernel(
    const float* __restrict__ k2, const float* __restrict__ v2,
    const float* __restrict__ qk2g, float* __restrict__ c2o, int b0)
{
    const int blk = blockIdx.x;          // bbe*8 + pi
    const int pi  = blk & 7;
    const int bbe = blk >> 3;            // bb*256 + e
    const int b   = b0 + (bbe >> 8);
    const int be  = (b << 8) | (bbe & 255);
    const int t   = threadIdx.x;

    __shared__ float s_part[800];
    __shared__ float s_v[3200];
    __shared__ float s_logit[32];
    float4* sv4 = (float4*)s_v;

    const size_t tb = ((size_t)(be * NN1 + pi * 2)) * 400;  // float4 offset; 800 f4 region
    const float4* kt  = (const float4*)k2 + tb;
    const float4* vt  = (const float4*)v2 + tb;
    const float4* qkb = (const float4*)qk2g + b * 25;

    const int i0 = t, i1 = t + 256, i2 = t + 512, i3 = t + 768;
    // issue everything up front
    float4 ka0 = kt[i0], ka1 = kt[i1], ka2 = kt[i2];
    float4 va0 = vt[i0], va1 = vt[i1], va2 = vt[i2];
    float4 ka3, va3;
    if (t < 32) { ka3 = kt[i3]; va3 = vt[i3]; }
    const int c0 = i0 % 25, c1 = i1 % 25, c2 = i2 % 25, c3 = i3 % 25;
    const float4 q0 = qkb[c0], q1 = qkb[c1], q2 = qkb[c2], q3 = qkb[c3];

    s_part[i0] = dot4(ka0, q0); sv4[i0] = va0;
    s_part[i1] = dot4(ka1, q1); sv4[i1] = va1;
    s_part[i2] = dot4(ka2, q2); sv4[i2] = va2;
    if (t < 32) { s_part[i3] = dot4(ka3, q3); sv4[i3] = va3; }
    __syncthreads();

    if (t < 32) {   // stride-25 reads: 25 coprime 32 -> conflict-free
        float acc = 0.f;
        #pragma unroll
        for (int c = 0; c < 25; ++c) acc += s_part[t * 25 + c];
        if (acc == 0.0f) acc = -10000.0f;
        s_logit[t] = acc >= 0.f ? acc : 0.01f * acc;   // leaky_relu
    }
    __syncthreads();

    const int half = t >> 7;             // 0: tile a, 1: tile b
    float lg = s_logit[half * 16 + (t & 15)];
    float mx = lg;
    mx = fmaxf(mx, __shfl_xor(mx, 1, 16));
    mx = fmaxf(mx, __shfl_xor(mx, 2, 16));
    mx = fmaxf(mx, __shfl_xor(mx, 4, 16));
    mx = fmaxf(mx, __shfl_xor(mx, 8, 16));
    const float e = __expf(lg - mx);
    float sm = e;
    sm += __shfl_xor(sm, 1, 16);
    sm += __shfl_xor(sm, 2, 16);
    sm += __shfl_xor(sm, 4, 16);
    sm += __shfl_xor(sm, 8, 16);
    float p = e / sm;
    if (p == 0.0625f) p = 0.f;           // where(attn == 1/n, 0)
    float pn[16];
    #pragma unroll
    for (int n = 0; n < 16; ++n) pn[n] = __shfl(p, n, 16);

    const int lt = t & 127;
    if (lt < DD) {
        const float* vb = s_v + half * 1600;
        float a = 0.f;
        #pragma unroll
        for (int n = 0; n < NN2; ++n) a += pn[n] * vb[n * DD + lt];
        c2o[((size_t)bbe * NN1 + pi * 2 + half) * DD + lt] = a;
    }
}

// ---------------------------------------------------------------------------
// dk1: one block per (bb,e). k1/v1/c2 all float4-staged, issued up front.
// ---------------------------------------------------------------------------
__global__ __launch_bounds__(256) void dk1_kernel(
    const float* __restrict__ k1, const float* __restrict__ v1,
    const float* __restrict__ c2i, const float* __restrict__ qk1g,
    float* __restrict__ comb, int b0)
{
    const int bbe = blockIdx.x;          // bb*256 + e
    const int b   = b0 + (bbe >> 8);
    const int be  = (b << 8) | (bbe & 255);
    const int t   = threadIdx.x;

    __shared__ float s_part[400];
    __shared__ float s_v[1600];
    __shared__ float s_c[1600];
    __shared__ float s_logit[16];
    float4* sv4 = (float4*)s_v;
    float4* sc4 = (float4*)s_c;

    const float4* kt  = (const float4*)k1 + (size_t)be * 400;
    const float4* vt  = (const float4*)v1 + (size_t)be * 400;
    const float4* ct  = (const float4*)c2i + (size_t)bbe * 400;
    const float4* qkb = (const float4*)qk1g + b * 25;

    const int i0 = t, i1 = t + 256;
    float4 ka0 = kt[i0], va0 = vt[i0], ca0 = ct[i0];
    float4 ka1, va1, ca1;
    if (t < 144) { ka1 = kt[i1]; va1 = vt[i1]; ca1 = ct[i1]; }
    const int c0 = i0 % 25, c1 = i1 % 25;
    const float4 q0 = qkb[c0], q1 = qkb[c1];

    s_part[i0] = dot4(ka0, q0); sv4[i0] = va0; sc4[i0] = ca0;
    if (t < 144) { s_part[i1] = dot4(ka1, q1); sv4[i1] = va1; sc4[i1] = ca1; }
    __syncthreads();

    if (t < 16) {
        float acc = 0.f;
        #pragma unroll
        for (int c = 0; c < 25; ++c) acc += s_part[t * 25 + c];
        if (acc == 0.0f) acc = -10000.0f;
        s_logit[t] = acc >= 0.f ? acc : 0.01f * acc;
    }
    __syncthreads();

    float lg = s_logit[t & 15];
    float mx = lg;
    mx = fmaxf(mx, __shfl_xor(mx, 1, 16));
    mx = fmaxf(mx, __shfl_xor(mx, 2, 16));
    mx = fmaxf(mx, __shfl_xor(mx, 4, 16));
    mx = fmaxf(mx, __shfl_xor(mx, 8, 16));
    const float e = __expf(lg - mx);
    float sm = e;
    sm += __shfl_xor(sm, 1, 16);
    sm += __shfl_xor(sm, 2, 16);
    sm += __shfl_xor(sm, 4, 16);
    sm += __shfl_xor(sm, 8, 16);
    float p = e / sm;
    if (p == 0.0625f) p = 0.f;
    float pn[16];
    #pragma unroll
    for (int n = 0; n < 16; ++n) pn[n] = __shfl(p, n, 16);

    if (t < 2 * DD) {
        float a = 0.f;
        if (t < DD) {
            #pragma unroll
            for (int n = 0; n < NN1; ++n) a += pn[n] * s_v[n * DD + t];
        } else {
            const int d = t - DD;
            #pragma unroll
            for (int n = 0; n < NN1; ++n) a += pn[n] * s_c[n * DD + d];
        }
        comb[(size_t)be * (2 * DD) + t] = a;
    }
}

// ---------------------------------------------------------------------------
// gather: one block per (b,s)
// ---------------------------------------------------------------------------
__global__ __launch_bounds__(64) void gather_kernel(
    const float* __restrict__ comb, const int* __restrict__ rk, float* __restrict__ out)
{
    const int bs = blockIdx.x;
    const int b  = bs >> 8;
    const int t  = threadIdx.x;
    const int r  = rk[bs];
    float* o = out + (size_t)bs * (2 * DD);
    if (r < 0) {
        for (int d = t; d < 2 * DD; d += 64) o[d] = 0.f;
    } else {
        const float* src = comb + (size_t)(b * EE + r) * (2 * DD);
        for (int d = t; d < 2 * DD; d += 64) o[d] = src[d];
    }
}

extern "C" void kernel_launch(void* const* d_in, const int* in_sizes, int n_in,
                              void* d_out, int out_size, void* d_ws, size_t ws_size,
                              hipStream_t stream)
{
    const int*   ent = (const int*)d_in[0];
    const float* q   = (const float*)d_in[1];
    const float* k1  = (const float*)d_in[2];
    const float* v1  = (const float*)d_in[3];
    const float* k2  = (const float*)d_in[4];
    const float* v2  = (const float*)d_in[5];
    const float* Wq2 = (const float*)d_in[6];
    const float* bq2 = (const float*)d_in[7];
    const float* Wk2 = (const float*)d_in[8];
    const float* Wq1 = (const float*)d_in[9];
    const float* bq1 = (const float*)d_in[10];
    const float* Wk1 = (const float*)d_in[11];
    float* out = (float*)d_out;

    float* ws   = (float*)d_ws;
    float* qk2  = ws;                          // [0, 1024)
    float* qk1  = ws + 1024;                   // [1024, 2048)
    int*   rk   = (int*)(ws + 2048);           // [2048, 4096) as ints
    float* comb = ws + 4096;                   // [4096, 4096+409600)
    float* c2   = ws + 4096 + 409600;          // per-b chunks of 409600 floats

    const size_t fixed = 4096 + 409600;        // floats
    const size_t perb  = (size_t)EE * NN1 * DD; // 409600 floats per batch
    size_t wsf = ws_size / sizeof(float);
    int kb = (wsf > fixed) ? (int)((wsf - fixed) / perb) : 1;
    if (kb < 1) kb = 1;
    if (kb > BB) kb = BB;

    prep_kernel<<<24, 256, 0, stream>>>(q, ent, Wq2, bq2, Wk2, Wq1, bq1, Wk1, qk2, qk1, rk);
    for (int b0 = 0; b0 < BB; b0 += kb) {
        const int nb = (BB - b0 < kb) ? (BB - b0) : kb;
        dk2_kernel<<<nb * EE * 8, 256, 0, stream>>>(k2, v2, qk2, c2, b0);
        dk1_kernel<<<nb * EE,     256, 0, stream>>>(k1, v1, c2, qk1, comb, b0);
    }
    gather_kernel<<<BB * SS, 64, 0, stream>>>(comb, rk, out);
}